// Round 13
// baseline (236.569 us; speedup 1.0000x reference)
//
#include <hip/hip_runtime.h>
#include <hip/hip_bf16.h>

// Problem constants (BertSelfAttention_979252544303)
#define SEQ   2048
#define BATCH 2
#define HID   1024
#define NHEAD 16
#define HDIM  64
#define BH    (BATCH * NHEAD)   // 32 flattened heads

using short4v  = __attribute__((ext_vector_type(4))) short;
using short8   = __attribute__((ext_vector_type(8))) short;
using floatx4  = __attribute__((ext_vector_type(4))) float;
using uint2v   = __attribute__((ext_vector_type(2))) unsigned int;

#define LOG2E 1.44269504f
#define SCALE_LOG2E (0.125f * LOG2E)   // (1/sqrt(64)) * log2(e)

// float -> bf16 (RNE) — used by preps/QKV epilogue (unchanged)
static __device__ __forceinline__ unsigned short f2bf(float f) {
    unsigned int u = __builtin_bit_cast(unsigned int, f);
    u += 0x7fffu + ((u >> 16) & 1u);
    return (unsigned short)(u >> 16);
}

static __device__ __forceinline__ float4 mul4(float4 a, float s) {
    return make_float4(a.x * s, a.y * s, a.z * s, a.w * s);
}

// raw v_exp_f32 (2^x). exp2f's overflow/denorm guard never triggers for our
// bounded scores; the guarded path executes the same v_exp_f32 -> identical
// results, fewer VALU ops. (proven v18)
#if __has_builtin(__builtin_amdgcn_exp2f)
#define EXP2(x) __builtin_amdgcn_exp2f(x)
#else
#define EXP2(x) exp2f(x)
#endif

// Pack two round-half-up bf16 into one dword: hi16(hi_)|hi16(lo_).
// perm selector 0x07060302: D = {hi_.b3, hi_.b2, lo_.b3, lo_.b2}.
// Rounding identical to v20's f2bf_hu (hi16 of u+0x8000) — 3 ops/pair.
#if __has_builtin(__builtin_amdgcn_perm)
#define PERMPACK(hi_, lo_) __builtin_amdgcn_perm((hi_), (lo_), 0x07060302u)
#else
#define PERMPACK(hi_, lo_) ((((hi_) & 0xffff0000u)) | ((lo_) >> 16))
#endif

// D = A(16x16 bf16) * B(16x16 bf16) + C  — per-wave MFMA, K=16
static __device__ __forceinline__ floatx4 mfma16x16x16(
    short4v a, short4v b, floatx4 c) {
#if __has_builtin(__builtin_amdgcn_mfma_f32_16x16x16bf16_1k)
    return __builtin_amdgcn_mfma_f32_16x16x16bf16_1k(a, b, c, 0, 0, 0);
#else
    floatx4 d;
    asm volatile("v_mfma_f32_16x16x16_bf16 %0, %1, %2, %3"
                 : "=v"(d) : "v"(a), "v"(b), "v"(c));
    return d;
#endif
}

#define GLD16(gp, lp)                                                        \
    __builtin_amdgcn_global_load_lds(                                        \
        (const __attribute__((address_space(1))) void*)(gp),                 \
        (__attribute__((address_space(3))) void*)(lp), 16, 0, 0)

// ---------------------------------------------------------------------------
// Prep 1: x fp32 [4096][1024] -> bf16 (straight). 1 float4 per thread.
// ---------------------------------------------------------------------------
__global__ __launch_bounds__(256) void convert_x(
    const float* __restrict__ x, unsigned short* __restrict__ xb)
{
    const int i = blockIdx.x * 256 + threadIdx.x;
    const float4 v = ((const float4*)x)[i];
    ushort4 o;
    o.x = f2bf(v.x); o.y = f2bf(v.y); o.z = f2bf(v.z); o.w = f2bf(v.w);
    ((ushort4*)xb)[i] = o;
}

// ---------------------------------------------------------------------------
// Prep 2: W fp32 [k][n] -> wt bf16 [n][k], tiled transpose. z selects Q/K/V.
// ---------------------------------------------------------------------------
__global__ __launch_bounds__(256) void transpose_w(
    const float* __restrict__ Wq, const float* __restrict__ Wk,
    const float* __restrict__ Wv, unsigned short* __restrict__ wt)
{
    const float* W = (blockIdx.z == 0) ? Wq : (blockIdx.z == 1) ? Wk : Wv;
    unsigned short* out = wt + (size_t)blockIdx.z * HID * HID;
    __shared__ float tile[32][33];
    const int tx = threadIdx.x & 31, ty = threadIdx.x >> 5;
    const int bx = blockIdx.x * 32, by = blockIdx.y * 32;
    #pragma unroll
    for (int j = 0; j < 4; ++j)
        tile[ty + j * 8][tx] = W[(size_t)(by + ty + j * 8) * HID + bx + tx];
    __syncthreads();
    #pragma unroll
    for (int j = 0; j < 4; ++j)
        out[(size_t)(bx + ty + j * 8) * HID + by + tx] = f2bf(tile[tx][ty + j * 8]);
}

// ---------------------------------------------------------------------------
// Kernel 1: fused QKV projection, bf16 MFMA, GLD16 ping-pong dbuf.
// Structure audit (round 9): this is the guide's m97 kernel (128^2 tile,
// BK=32, dbuf, 1 barrier/K-step, 4 GLD16/thread/step, 16 MFMA/wave/step).
// m102's shape curve puts that structure at ~320 TF for our N=1024-class
// shape (~81 µs for 25.8 GF) — near its structural/shape local optimum.
// The proven escapes don't apply: 256^2 8-phase needs >=256 blocks (we'd
// have 192 at this N); BK=64-dbuf hits m132's 64 KB occupancy cliff.
// Left as-is.
// ---------------------------------------------------------------------------
#define CTP 136   // C-tile pitch: 128 + 8 pad
__global__ __launch_bounds__(256) void qkv_mfma(
    const unsigned short* __restrict__ xb,
    const unsigned short* __restrict__ wt,
    const float* __restrict__ bq, const float* __restrict__ bk,
    const float* __restrict__ bv,
    unsigned short* __restrict__ ws_out)
{
    const int bn = blockIdx.x;   // 0..7
    const int bm = blockIdx.y;   // 0..31
    const int z  = blockIdx.z;   // 0..2
    const unsigned short* Bt = wt + (size_t)z * HID * HID;
    const float* bias = (z == 0) ? bq : (z == 1) ? bk : bv;
    unsigned short* out = ws_out + (size_t)z * (size_t)BH * SEQ * HDIM;

    const int t    = threadIdx.x;
    const int wave = t >> 6;
    const int lane = t & 63;
    const int l15  = lane & 15;
    const int quad = lane >> 4;
    const int wm   = (wave >> 1) * 64;
    const int wn   = (wave & 1) * 64;

    // union: [0,16384) = As dbuf + Bs dbuf (4x 4096 elems); epilogue C tile
    // needs 128*CTP = 17408 elems.
    __shared__ __align__(16) unsigned short smem[128 * CTP];
    #define ASB(buf) (smem + (buf) * 4096)
    #define BSB(buf) (smem + 8192 + (buf) * 4096)

    floatx4 acc[4][4];
    #pragma unroll
    for (int i = 0; i < 4; ++i)
        #pragma unroll
        for (int j = 0; j < 4; ++j)
            acc[i][j] = (floatx4){0.f, 0.f, 0.f, 0.f};

    const int lrow = lane >> 2;
    const int lcol = (lane & 3) * 8;

    #define QKV_STAGE(kt, buf)                                                  \
        do {                                                                    \
            _Pragma("unroll")                                                   \
            for (int ee = 0; ee < 2; ++ee) {                                    \
                const int e = wave * 2 + ee;                                    \
                const unsigned short* ga = xb +                                 \
                    (size_t)(bm * 128 + e * 16 + lrow) * HID + (kt) * 32 + lcol;\
                const unsigned short* gb = Bt +                                 \
                    (size_t)(bn * 128 + e * 16 + lrow) * HID + (kt) * 32 + lcol;\
                GLD16(ga, (char*)ASB(buf) + e * 1024);                          \
                GLD16(gb, (char*)BSB(buf) + e * 1024);                          \
            }                                                                   \
        } while (0)

    QKV_STAGE(0, 0);

    for (int kt = 0; kt < HID / 32; ++kt) {
        const int buf = kt & 1;
        __syncthreads();   // drains DMA for tile kt; syncs prev compute reads
        if (kt + 1 < HID / 32)
            QKV_STAGE(kt + 1, buf ^ 1);   // overlaps with compute below

        short8 af[4], bf[4];
        #pragma unroll
        for (int mt = 0; mt < 4; ++mt)
            af[mt] = *(const short8*)&ASB(buf)[(wm + mt * 16 + l15) * 32 + quad * 8];
        #pragma unroll
        for (int nt = 0; nt < 4; ++nt)
            bf[nt] = *(const short8*)&BSB(buf)[(wn + nt * 16 + l15) * 32 + quad * 8];
        #pragma unroll
        for (int mt = 0; mt < 4; ++mt)
            #pragma unroll
            for (int nt = 0; nt < 4; ++nt)
                acc[mt][nt] = __builtin_amdgcn_mfma_f32_16x16x32_bf16(
                    af[mt], bf[nt], acc[mt][nt], 0, 0, 0);
    }
    #undef QKV_STAGE

    if (z < 2) {
        #pragma unroll
        for (int nt = 0; nt < 4; ++nt) {
            const int n_g = bn * 128 + wn + nt * 16 + l15;
            const float bsv = bias[n_g];
            const int h = n_g >> 6;
            const int d = n_g & 63;
            #pragma unroll
            for (int mt = 0; mt < 4; ++mt) {
                #pragma unroll
                for (int r = 0; r < 4; ++r) {
                    const int m_g = bm * 128 + wm + mt * 16 + quad * 4 + r;
                    const int s  = m_g >> 1;
                    const int bb = m_g & 1;
                    out[((size_t)(bb * NHEAD + h) * SEQ + s) * HDIM + d] =
                        f2bf(acc[mt][nt][r] + bsv);
                }
            }
        }
    } else {
        // ---- V: LDS bounce -> coalesced [bh][d][s] stores ----
        __syncthreads();   // all frag reads from As/Bs complete before reuse
        #pragma unroll
        for (int nt = 0; nt < 4; ++nt) {
            const int n_l = wn + nt * 16 + l15;
            const float bsv = bias[bn * 128 + n_l];
            #pragma unroll
            for (int mt = 0; mt < 4; ++mt) {
                #pragma unroll
                for (int r = 0; r < 4; ++r) {
                    const int m_l = wm + mt * 16 + quad * 4 + r;
                    // m -> (s_l, bb): s interleaved with batch (BATCH==2)
                    smem[n_l * CTP + (m_l & 1) * 64 + (m_l >> 1)] =
                        f2bf(acc[mt][nt][r] + bsv);
                }
            }
        }
        __syncthreads();
        // read back: thread t owns row (n_l = t>>1, bb = t&1) = 64 s * 2B
        const int n_l = t >> 1;
        const int b2  = t & 1;
        const int n_g = bn * 128 + n_l;
        const int h   = n_g >> 6;
        const int d   = n_g & 63;
        const unsigned short* src = smem + n_l * CTP + b2 * 64;
        unsigned short* dst =
            out + ((size_t)(b2 * NHEAD + h) * HDIM + d) * SEQ + bm * 64;
        #pragma unroll
        for (int c = 0; c < 8; ++c)    // 8 x 16B = 128 B (one full line set)
            *(uint4*)(dst + c * 8) = *(const uint4*)(src + c * 8);
    }
}
#undef CTP

// ---------------------------------------------------------------------------
// Kernel 2: flash attention v21 = v20 (dbuf, 1 barrier/tile, mask prefetch,
// XOR-swizzled LDS, 2-deep mt-pipeline, setprio, raw EXP2, half-up bf16)
// with two final instruction-count cuts in SMPV:
//   (a) v_perm_b32 packing: d = perm(b1, b0, 0x07060302) with b=bits(pv)+
//       0x8000 — 3 ops/pair vs ~5-6 (add+shift x2 + repack). Rounding is
//       BIT-IDENTICAL to v20's f2bf_hu (hi16 of u+0x8000). Plain integer
//       builtin + C fallback; no inline asm (v10/v19's cvt_pk abandoned).
//       The dword->short4v bit_cast A-frag path is proven sound (v10
//       produced sane-but-biased values through it; its error was the RTZ
//       rounding itself, which perm does not share).
//   (b) deferred lst: accumulate into float4 lacc (4 independent chains),
//       reduce once in the epilogue. Same add count, no serial chain;
//       reassociation shift ~1e-6 relative (threshold margin 4x).
//   Saves ~16-24 issue cy/wave-tile (~4% of the ~95%-subscribed budget).
//   If <2 µs: structure confirmed issue-mix-bound; session freezes here
//   (remaining escape = full m214 8-wave/32x32 rewrite, out of budget).
// 256 threads, 4 waves x 16 q-rows, grid (32 qb, 32 heads) = 1024 blocks.
// q,kp: [bh][s][d] bf16; vt: [bh][d][s] bf16; mask: [B][1][S][S] fp32.
// ---------------------------------------------------------------------------
__global__ __launch_bounds__(256) void attn_v21(
    const unsigned short* __restrict__ q,
    const unsigned short* __restrict__ kp,
    const unsigned short* __restrict__ vt,
    const float* __restrict__ mask,
    float* __restrict__ out)
{
    const int qb   = blockIdx.x;   // 0..31 query tile (64 rows)
    const int n    = blockIdx.y;   // 0..31 flattened head
    const int t    = threadIdx.x;
    const int wave = t >> 6;
    const int lane = t & 63;
    const int l15  = lane & 15;
    const int quad = lane >> 4;
    const int bb   = n >> 4;       // batch
    const int hh   = n & 15;       // head

    // double-buffered 64x64 bf16 tiles, 128 B rows, XOR-swizzled
    __shared__ __align__(16) unsigned short Ks[2][64 * 64];
    __shared__ __align__(16) unsigned short Vs[2][64 * 64];

    // ---- Q fragments straight from global (one-time) ----
    const unsigned short* qbase = q + ((size_t)n * SEQ + qb * 64) * HDIM;
    short8 Qf[2];
    #pragma unroll
    for (int ks = 0; ks < 2; ++ks)
        Qf[ks] = *(const short8*)(qbase +
            (size_t)(wave * 16 + l15) * HDIM + ks * 32 + quad * 8);

    floatx4 Of[4];
    #pragma unroll
    for (int nt = 0; nt < 4; ++nt) Of[nt] = (floatx4){0.f, 0.f, 0.f, 0.f};
    floatx4 lacc = (floatx4){0.f, 0.f, 0.f, 0.f};   // deferred l-sum (4 chains)

    const unsigned short* kbase = kp + (size_t)n * SEQ * HDIM;
    const unsigned short* vbase = vt + (size_t)n * HDIM * SEQ;
    const float* mrow = mask + ((size_t)bb * SEQ + qb * 64 + wave * 16 + l15) * SEQ;

    // per-thread staging addresses (two 8-bf16 chunks each for K and V)
    const int c0 = t,        r0 = c0 >> 3, o0 = (c0 & 7) * 8;
    const int c1 = t + 256,  r1 = c1 >> 3, o1 = (c1 & 7) * 8;
    // swizzled LDS byte destinations for the staging writes
    const int sw0 = r0 * 128 + ((o0 * 2) ^ ((r0 & 7) << 4));
    const int sw1 = r1 * 128 + ((o1 * 2) ^ ((r1 & 7) << 4));
    // read-side swizzle term (row & 7 == l15 & 7 for all fragment reads)
    const int rsw = (l15 & 7) << 4;

    uint4 kreg0, kreg1, vreg0, vreg1;
    #define LOADT(tl)                                                          \
        do {                                                                   \
            const unsigned short* kb_ = kbase + (size_t)((tl) * 64) * HDIM;    \
            const unsigned short* vb_ = vbase + (tl) * 64;                     \
            kreg0 = *(const uint4*)(kb_ + (size_t)r0 * HDIM + o0);             \
            kreg1 = *(const uint4*)(kb_ + (size_t)r1 * HDIM + o1);             \
            vreg0 = *(const uint4*)(vb_ + (size_t)r0 * SEQ + o0);              \
            vreg1 = *(const uint4*)(vb_ + (size_t)r1 * SEQ + o1);              \
        } while (0)

    // ---- prologue: tile 0 -> buf 0; tile 1 -> regs; mask tile 0 ----
    LOADT(0);
    *(uint4*)((char*)Ks[0] + sw0) = kreg0;
    *(uint4*)((char*)Ks[0] + sw1) = kreg1;
    *(uint4*)((char*)Vs[0] + sw0) = vreg0;
    *(uint4*)((char*)Vs[0] + sw1) = vreg1;
    LOADT(1);
    float4 mreg[4], mnext[4];
    #pragma unroll
    for (int mt = 0; mt < 4; ++mt)
        mreg[mt] = mul4(*(const float4*)(mrow + mt * 16 + quad * 4), LOG2E);
    __syncthreads();   // buf0 visible (also drains tile-1 loads; one-time)

    // QK^T for one 16-key subtile into a named register (static mt only)
    #define KQK(mt, CC)                                                        \
        do {                                                                   \
            short8 a0_ = *(const short8*)(KsB + ((mt) * 16 + l15) * 128 +      \
                                          ((quad * 16) ^ rsw));                \
            short8 a1_ = *(const short8*)(KsB + ((mt) * 16 + l15) * 128 +      \
                                          ((64 + quad * 16) ^ rsw));           \
            floatx4 t_ = (floatx4){0.f, 0.f, 0.f, 0.f};                        \
            t_ = __builtin_amdgcn_mfma_f32_16x16x32_bf16(a0_, Qf[0], t_,       \
                                                         0, 0, 0);             \
            t_ = __builtin_amdgcn_mfma_f32_16x16x32_bf16(a1_, Qf[1], t_,       \
                                                         0, 0, 0);             \
            (CC) = t_;                                                         \
        } while (0)

    // softmax + PV for one subtile. Round-half-up bf16 (== v20's f2bf_hu
    // bit-for-bit) via add+perm; lacc accumulates the unrounded pv in 4
    // independent chains (reduced once in the epilogue).
    #define SMPV(mt, CC)                                                       \
        do {                                                                   \
            const float4 mv = mreg[mt];   /* already * LOG2E */                \
            const float pv0 = EXP2(fmaf((CC)[0], SCALE_LOG2E, mv.x));          \
            const float pv1 = EXP2(fmaf((CC)[1], SCALE_LOG2E, mv.y));          \
            const float pv2 = EXP2(fmaf((CC)[2], SCALE_LOG2E, mv.z));          \
            const float pv3 = EXP2(fmaf((CC)[3], SCALE_LOG2E, mv.w));          \
            lacc[0] += pv0; lacc[1] += pv1;                                    \
            lacc[2] += pv2; lacc[3] += pv3;                                    \
            const unsigned int b0_ =                                           \
                __builtin_bit_cast(unsigned int, pv0) + 0x8000u;               \
            const unsigned int b1_ =                                           \
                __builtin_bit_cast(unsigned int, pv1) + 0x8000u;               \
            const unsigned int b2_ =                                           \
                __builtin_bit_cast(unsigned int, pv2) + 0x8000u;               \
            const unsigned int b3_ =                                           \
                __builtin_bit_cast(unsigned int, pv3) + 0x8000u;               \
            const uint2v dd_ = {PERMPACK(b1_, b0_), PERMPACK(b3_, b2_)};       \
            const short4v Af = __builtin_bit_cast(short4v, dd_);               \
            _Pragma("unroll")                                                  \
            for (int nt = 0; nt < 4; ++nt) {                                   \
                short4v Bf = *(const short4v*)(VsB + (nt * 16 + l15) * 128 +   \
                                               (((mt) * 32 + quad * 8) ^ rsw));\
                Of[nt] = mfma16x16x16(Af, Bf, Of[nt]);                         \
            }                                                                  \
        } while (0)

    for (int kt = 0; kt < SEQ / 64; ++kt) {
        const int buf = kt & 1;
        char* const KsB = (char*)Ks[buf];
        char* const VsB = (char*)Vs[buf];

        if (kt + 1 < SEQ / 64) {   // phase A: regs(tile kt+1) -> buf^1
            char* const KsW = (char*)Ks[buf ^ 1];
            char* const VsW = (char*)Vs[buf ^ 1];
            *(uint4*)(KsW + sw0) = kreg0;
            *(uint4*)(KsW + sw1) = kreg1;
            *(uint4*)(VsW + sw0) = vreg0;
            *(uint4*)(VsW + sw1) = vreg1;
        }
        if (kt + 2 < SEQ / 64)     // phase B: issue loads for tile kt+2
            LOADT(kt + 2);
        if (kt + 1 < SEQ / 64) {   // mask prefetch for tile kt+1
            #pragma unroll
            for (int mt = 0; mt < 4; ++mt)
                mnext[mt] = *(const float4*)(mrow + (kt + 1) * 64 + mt * 16 + quad * 4);
        }

        // ---- 2-deep mt-pipeline: QK(mt+1) in flight under softmax+PV(mt) --
        // T5: raise wave priority through the MFMA-dense region.
        __builtin_amdgcn_s_setprio(1);
        {
            floatx4 cA, cB;
            KQK(0, cA);
            KQK(1, cB);
            SMPV(0, cA);
            KQK(2, cA);
            SMPV(1, cB);
            KQK(3, cB);
            SMPV(2, cA);
            SMPV(3, cB);
        }
        __builtin_amdgcn_s_setprio(0);

        if (kt + 1 < SEQ / 64) {   // fold LOG2E (off critical path)
            #pragma unroll
            for (int mt = 0; mt < 4; ++mt) mreg[mt] = mul4(mnext[mt], LOG2E);
        }
        __syncthreads();   // ONE barrier: phase-A writes visible; buf free
    }
    #undef LOADT
    #undef KQK
    #undef SMPV

    // ---- epilogue: fold lacc, reduce l across quads, normalize, store ----
    float lst = (lacc[0] + lacc[1]) + (lacc[2] + lacc[3]);
    lst += __shfl_xor(lst, 16);
    lst += __shfl_xor(lst, 32);   // lane with l15=q now holds full row sum
    #pragma unroll
    for (int r = 0; r < 4; ++r) {
        const float lrow = __shfl(lst, quad * 4 + r);   // row q = quad*4+r
        const float inv  = 1.0f / lrow;
        const int s = qb * 64 + wave * 16 + quad * 4 + r;
        float* orow = out + ((size_t)s * BATCH + bb) * HID + hh * 64;
        #pragma unroll
        for (int nt = 0; nt < 4; ++nt)
            orow[nt * 16 + l15] = Of[nt][r] * inv;
    }
}

// ---------------------------------------------------------------------------
extern "C" void kernel_launch(void* const* d_in, const int* in_sizes, int n_in,
                              void* d_out, int out_size, void* d_ws, size_t ws_size,
                              hipStream_t stream) {
    const float* x    = (const float*)d_in[0];
    const float* mask = (const float*)d_in[1];
    const float* Wq   = (const float*)d_in[2];
    const float* bq   = (const float*)d_in[3];
    const float* Wk   = (const float*)d_in[4];
    const float* bk   = (const float*)d_in[5];
    const float* Wv   = (const float*)d_in[6];
    const float* bv   = (const float*)d_in[7];
    float* out = (float*)d_out;

    const size_t per = (size_t)BH * SEQ * HDIM;   // 4,194,304 elems (8 MB bf16)
    unsigned short* qw = (unsigned short*)d_ws;   // 8 MB
    unsigned short* kw = qw + per;                // 8 MB
    unsigned short* vw = kw + per;                // 8 MB (V transposed [bh][d][s])
    unsigned short* xb = vw + per;                // 8 MB (x bf16)
    unsigned short* wt = xb + per;                // 6 MB (3x W^T bf16)

    convert_x<<<dim3(SEQ * BATCH * HID / 4 / 256), dim3(256), 0, stream>>>(x, xb);
    transpose_w<<<dim3(32, 32, 3), dim3(256), 0, stream>>>(Wq, Wk, Wv, wt);

    qkv_mfma<<<dim3(HID / 128, SEQ * BATCH / 128, 3), dim3(256), 0, stream>>>(
        xb, wt, bq, bk, bv, qw);

    attn_v21<<<dim3(SEQ / 64, BH), dim3(256), 0, stream>>>(qw, kw, vw, mask, out);
}

// Round 14
// 229.476 us; speedup vs baseline: 1.0309x; 1.0309x over previous
//
#include <hip/hip_runtime.h>
#include <hip/hip_bf16.h>

// Problem constants (BertSelfAttention_979252544303)
#define SEQ   2048
#define BATCH 2
#define HID   1024
#define NHEAD 16
#define HDIM  64
#define BH    (BATCH * NHEAD)   // 32 flattened heads

using short4v  = __attribute__((ext_vector_type(4))) short;
using short8   = __attribute__((ext_vector_type(8))) short;
using floatx4  = __attribute__((ext_vector_type(4))) float;

#define LOG2E 1.44269504f
#define SCALE_LOG2E (0.125f * LOG2E)   // (1/sqrt(64)) * log2(e)

// float -> bf16 (RNE) — used by preps/QKV epilogue (unchanged)
static __device__ __forceinline__ unsigned short f2bf(float f) {
    unsigned int u = __builtin_bit_cast(unsigned int, f);
    u += 0x7fffu + ((u >> 16) & 1u);
    return (unsigned short)(u >> 16);
}

// float -> bf16 (round-half-up): 2 ops vs RNE's 4. Differs from RNE only on
// exact ties (low 16 bits == 0x8000, p ~ 2^-16/value) — negligible at our
// 4.9e-4 operating point. Valid for the attn P-values (always > 0, finite).
static __device__ __forceinline__ unsigned short f2bf_hu(float f) {
    return (unsigned short)((__builtin_bit_cast(unsigned int, f) + 0x8000u) >> 16);
}

static __device__ __forceinline__ float4 mul4(float4 a, float s) {
    return make_float4(a.x * s, a.y * s, a.z * s, a.w * s);
}

// raw v_exp_f32 (2^x). exp2f's overflow/denorm guard never triggers for our
// bounded scores; the guarded path executes the same v_exp_f32 -> identical
// results, fewer VALU ops. (proven v18)
#if __has_builtin(__builtin_amdgcn_exp2f)
#define EXP2(x) __builtin_amdgcn_exp2f(x)
#else
#define EXP2(x) exp2f(x)
#endif

// D = A(16x16 bf16) * B(16x16 bf16) + C  — per-wave MFMA, K=16
static __device__ __forceinline__ floatx4 mfma16x16x16(
    short4v a, short4v b, floatx4 c) {
#if __has_builtin(__builtin_amdgcn_mfma_f32_16x16x16bf16_1k)
    return __builtin_amdgcn_mfma_f32_16x16x16bf16_1k(a, b, c, 0, 0, 0);
#else
    floatx4 d;
    asm volatile("v_mfma_f32_16x16x16_bf16 %0, %1, %2, %3"
                 : "=v"(d) : "v"(a), "v"(b), "v"(c));
    return d;
#endif
}

#define GLD16(gp, lp)                                                        \
    __builtin_amdgcn_global_load_lds(                                        \
        (const __attribute__((address_space(1))) void*)(gp),                 \
        (__attribute__((address_space(3))) void*)(lp), 16, 0, 0)

// ---------------------------------------------------------------------------
// Prep 1: x fp32 [4096][1024] -> bf16 (straight). 1 float4 per thread.
// ---------------------------------------------------------------------------
__global__ __launch_bounds__(256) void convert_x(
    const float* __restrict__ x, unsigned short* __restrict__ xb)
{
    const int i = blockIdx.x * 256 + threadIdx.x;
    const float4 v = ((const float4*)x)[i];
    ushort4 o;
    o.x = f2bf(v.x); o.y = f2bf(v.y); o.z = f2bf(v.z); o.w = f2bf(v.w);
    ((ushort4*)xb)[i] = o;
}

// ---------------------------------------------------------------------------
// Prep 2: W fp32 [k][n] -> wt bf16 [n][k], tiled transpose. z selects Q/K/V.
// ---------------------------------------------------------------------------
__global__ __launch_bounds__(256) void transpose_w(
    const float* __restrict__ Wq, const float* __restrict__ Wk,
    const float* __restrict__ Wv, unsigned short* __restrict__ wt)
{
    const float* W = (blockIdx.z == 0) ? Wq : (blockIdx.z == 1) ? Wk : Wv;
    unsigned short* out = wt + (size_t)blockIdx.z * HID * HID;
    __shared__ float tile[32][33];
    const int tx = threadIdx.x & 31, ty = threadIdx.x >> 5;
    const int bx = blockIdx.x * 32, by = blockIdx.y * 32;
    #pragma unroll
    for (int j = 0; j < 4; ++j)
        tile[ty + j * 8][tx] = W[(size_t)(by + ty + j * 8) * HID + bx + tx];
    __syncthreads();
    #pragma unroll
    for (int j = 0; j < 4; ++j)
        out[(size_t)(bx + ty + j * 8) * HID + by + tx] = f2bf(tile[tx][ty + j * 8]);
}

// ---------------------------------------------------------------------------
// Kernel 1: fused QKV projection, bf16 MFMA, GLD16 ping-pong dbuf.
// Structure audit (round 9): this is the guide's m97 kernel (128^2 tile,
// BK=32, dbuf, 1 barrier/K-step, 4 GLD16/thread/step, 16 MFMA/wave/step).
// m102's shape curve puts that structure at ~320 TF for our N=1024-class
// shape (~81 µs for 25.8 GF) — near its structural/shape local optimum.
// The proven escapes don't apply: 256^2 8-phase needs >=256 blocks (we'd
// have 192 at this N); BK=64-dbuf hits m132's 64 KB occupancy cliff.
// Left as-is.
// ---------------------------------------------------------------------------
#define CTP 136   // C-tile pitch: 128 + 8 pad
__global__ __launch_bounds__(256) void qkv_mfma(
    const unsigned short* __restrict__ xb,
    const unsigned short* __restrict__ wt,
    const float* __restrict__ bq, const float* __restrict__ bk,
    const float* __restrict__ bv,
    unsigned short* __restrict__ ws_out)
{
    const int bn = blockIdx.x;   // 0..7
    const int bm = blockIdx.y;   // 0..31
    const int z  = blockIdx.z;   // 0..2
    const unsigned short* Bt = wt + (size_t)z * HID * HID;
    const float* bias = (z == 0) ? bq : (z == 1) ? bk : bv;
    unsigned short* out = ws_out + (size_t)z * (size_t)BH * SEQ * HDIM;

    const int t    = threadIdx.x;
    const int wave = t >> 6;
    const int lane = t & 63;
    const int l15  = lane & 15;
    const int quad = lane >> 4;
    const int wm   = (wave >> 1) * 64;
    const int wn   = (wave & 1) * 64;

    // union: [0,16384) = As dbuf + Bs dbuf (4x 4096 elems); epilogue C tile
    // needs 128*CTP = 17408 elems.
    __shared__ __align__(16) unsigned short smem[128 * CTP];
    #define ASB(buf) (smem + (buf) * 4096)
    #define BSB(buf) (smem + 8192 + (buf) * 4096)

    floatx4 acc[4][4];
    #pragma unroll
    for (int i = 0; i < 4; ++i)
        #pragma unroll
        for (int j = 0; j < 4; ++j)
            acc[i][j] = (floatx4){0.f, 0.f, 0.f, 0.f};

    const int lrow = lane >> 2;
    const int lcol = (lane & 3) * 8;

    #define QKV_STAGE(kt, buf)                                                  \
        do {                                                                    \
            _Pragma("unroll")                                                   \
            for (int ee = 0; ee < 2; ++ee) {                                    \
                const int e = wave * 2 + ee;                                    \
                const unsigned short* ga = xb +                                 \
                    (size_t)(bm * 128 + e * 16 + lrow) * HID + (kt) * 32 + lcol;\
                const unsigned short* gb = Bt +                                 \
                    (size_t)(bn * 128 + e * 16 + lrow) * HID + (kt) * 32 + lcol;\
                GLD16(ga, (char*)ASB(buf) + e * 1024);                          \
                GLD16(gb, (char*)BSB(buf) + e * 1024);                          \
            }                                                                   \
        } while (0)

    QKV_STAGE(0, 0);

    for (int kt = 0; kt < HID / 32; ++kt) {
        const int buf = kt & 1;
        __syncthreads();   // drains DMA for tile kt; syncs prev compute reads
        if (kt + 1 < HID / 32)
            QKV_STAGE(kt + 1, buf ^ 1);   // overlaps with compute below

        short8 af[4], bf[4];
        #pragma unroll
        for (int mt = 0; mt < 4; ++mt)
            af[mt] = *(const short8*)&ASB(buf)[(wm + mt * 16 + l15) * 32 + quad * 8];
        #pragma unroll
        for (int nt = 0; nt < 4; ++nt)
            bf[nt] = *(const short8*)&BSB(buf)[(wn + nt * 16 + l15) * 32 + quad * 8];
        #pragma unroll
        for (int mt = 0; mt < 4; ++mt)
            #pragma unroll
            for (int nt = 0; nt < 4; ++nt)
                acc[mt][nt] = __builtin_amdgcn_mfma_f32_16x16x32_bf16(
                    af[mt], bf[nt], acc[mt][nt], 0, 0, 0);
    }
    #undef QKV_STAGE

    if (z < 2) {
        #pragma unroll
        for (int nt = 0; nt < 4; ++nt) {
            const int n_g = bn * 128 + wn + nt * 16 + l15;
            const float bsv = bias[n_g];
            const int h = n_g >> 6;
            const int d = n_g & 63;
            #pragma unroll
            for (int mt = 0; mt < 4; ++mt) {
                #pragma unroll
                for (int r = 0; r < 4; ++r) {
                    const int m_g = bm * 128 + wm + mt * 16 + quad * 4 + r;
                    const int s  = m_g >> 1;
                    const int bb = m_g & 1;
                    out[((size_t)(bb * NHEAD + h) * SEQ + s) * HDIM + d] =
                        f2bf(acc[mt][nt][r] + bsv);
                }
            }
        }
    } else {
        // ---- V: LDS bounce -> coalesced [bh][d][s] stores ----
        __syncthreads();   // all frag reads from As/Bs complete before reuse
        #pragma unroll
        for (int nt = 0; nt < 4; ++nt) {
            const int n_l = wn + nt * 16 + l15;
            const float bsv = bias[bn * 128 + n_l];
            #pragma unroll
            for (int mt = 0; mt < 4; ++mt) {
                #pragma unroll
                for (int r = 0; r < 4; ++r) {
                    const int m_l = wm + mt * 16 + quad * 4 + r;
                    // m -> (s_l, bb): s interleaved with batch (BATCH==2)
                    smem[n_l * CTP + (m_l & 1) * 64 + (m_l >> 1)] =
                        f2bf(acc[mt][nt][r] + bsv);
                }
            }
        }
        __syncthreads();
        // read back: thread t owns row (n_l = t>>1, bb = t&1) = 64 s * 2B
        const int n_l = t >> 1;
        const int b2  = t & 1;
        const int n_g = bn * 128 + n_l;
        const int h   = n_g >> 6;
        const int d   = n_g & 63;
        const unsigned short* src = smem + n_l * CTP + b2 * 64;
        unsigned short* dst =
            out + ((size_t)(b2 * NHEAD + h) * HDIM + d) * SEQ + bm * 64;
        #pragma unroll
        for (int c = 0; c < 8; ++c)    // 8 x 16B = 128 B (one full line set)
            *(uint4*)(dst + c * 8) = *(const uint4*)(src + c * 8);
    }
}
#undef CTP

// ---------------------------------------------------------------------------
// Kernel 2: flash attention v20 (SESSION BEST, frozen) = dbuf, 1 barrier/
// tile, mask prefetch, XOR-swizzled LDS, 2-deep mt-pipeline, setprio, raw
// EXP2, 2-op half-up bf16 P-conversion.
//   Round-13 revert-to-best: v21's perm-pack + deferred-lst cut VALUBusy
//   39.7->36.6 but raised VGPR 64->76, dropping occupancy 33->25 — net
//   neutral-to-negative. Third confirmation of the issue-mix-bound model:
//   per wave-tile issue cost (~trans 128 + VALU ~170 + MFMA ~103 + LDS ~48
//   cy) x 4 waves/SIMD ~ 95% of measured wall; removing VALU ops just
//   converts to stalls elsewhere, and register side-effects eat the rest.
//   Session ladder (attn): v8 127 -> v9 swizzle 124 (conflicts 25.2M->8.4M)
//   -> v11 mask-prefetch 109 -> v17 2-deep pipeline 105 -> v18 setprio+EXP2
//   101.5 -> v20 f2bf_hu ~102 (best total 232.3). Refuted: team-split
//   occupancy (v13/v14), barrier count (v15), phase-batch (v16), cvt_pk
//   (v10/v19, 2 failures), perm-pack (v21). Remaining headroom is the full
//   m214-style 8-wave 32x32 co-designed rewrite — out of session budget.
// 256 threads, 4 waves x 16 q-rows, grid (32 qb, 32 heads) = 1024 blocks.
// q,kp: [bh][s][d] bf16; vt: [bh][d][s] bf16; mask: [B][1][S][S] fp32.
// ---------------------------------------------------------------------------
__global__ __launch_bounds__(256) void attn_v20(
    const unsigned short* __restrict__ q,
    const unsigned short* __restrict__ kp,
    const unsigned short* __restrict__ vt,
    const float* __restrict__ mask,
    float* __restrict__ out)
{
    const int qb   = blockIdx.x;   // 0..31 query tile (64 rows)
    const int n    = blockIdx.y;   // 0..31 flattened head
    const int t    = threadIdx.x;
    const int wave = t >> 6;
    const int lane = t & 63;
    const int l15  = lane & 15;
    const int quad = lane >> 4;
    const int bb   = n >> 4;       // batch
    const int hh   = n & 15;       // head

    // double-buffered 64x64 bf16 tiles, 128 B rows, XOR-swizzled
    __shared__ __align__(16) unsigned short Ks[2][64 * 64];
    __shared__ __align__(16) unsigned short Vs[2][64 * 64];

    // ---- Q fragments straight from global (one-time) ----
    const unsigned short* qbase = q + ((size_t)n * SEQ + qb * 64) * HDIM;
    short8 Qf[2];
    #pragma unroll
    for (int ks = 0; ks < 2; ++ks)
        Qf[ks] = *(const short8*)(qbase +
            (size_t)(wave * 16 + l15) * HDIM + ks * 32 + quad * 8);

    floatx4 Of[4];
    #pragma unroll
    for (int nt = 0; nt < 4; ++nt) Of[nt] = (floatx4){0.f, 0.f, 0.f, 0.f};
    float lst = 0.0f;

    const unsigned short* kbase = kp + (size_t)n * SEQ * HDIM;
    const unsigned short* vbase = vt + (size_t)n * HDIM * SEQ;
    const float* mrow = mask + ((size_t)bb * SEQ + qb * 64 + wave * 16 + l15) * SEQ;

    // per-thread staging addresses (two 8-bf16 chunks each for K and V)
    const int c0 = t,        r0 = c0 >> 3, o0 = (c0 & 7) * 8;
    const int c1 = t + 256,  r1 = c1 >> 3, o1 = (c1 & 7) * 8;
    // swizzled LDS byte destinations for the staging writes
    const int sw0 = r0 * 128 + ((o0 * 2) ^ ((r0 & 7) << 4));
    const int sw1 = r1 * 128 + ((o1 * 2) ^ ((r1 & 7) << 4));
    // read-side swizzle term (row & 7 == l15 & 7 for all fragment reads)
    const int rsw = (l15 & 7) << 4;

    uint4 kreg0, kreg1, vreg0, vreg1;
    #define LOADT(tl)                                                          \
        do {                                                                   \
            const unsigned short* kb_ = kbase + (size_t)((tl) * 64) * HDIM;    \
            const unsigned short* vb_ = vbase + (tl) * 64;                     \
            kreg0 = *(const uint4*)(kb_ + (size_t)r0 * HDIM + o0);             \
            kreg1 = *(const uint4*)(kb_ + (size_t)r1 * HDIM + o1);             \
            vreg0 = *(const uint4*)(vb_ + (size_t)r0 * SEQ + o0);              \
            vreg1 = *(const uint4*)(vb_ + (size_t)r1 * SEQ + o1);              \
        } while (0)

    // ---- prologue: tile 0 -> buf 0; tile 1 -> regs; mask tile 0 ----
    LOADT(0);
    *(uint4*)((char*)Ks[0] + sw0) = kreg0;
    *(uint4*)((char*)Ks[0] + sw1) = kreg1;
    *(uint4*)((char*)Vs[0] + sw0) = vreg0;
    *(uint4*)((char*)Vs[0] + sw1) = vreg1;
    LOADT(1);
    float4 mreg[4], mnext[4];
    #pragma unroll
    for (int mt = 0; mt < 4; ++mt)
        mreg[mt] = mul4(*(const float4*)(mrow + mt * 16 + quad * 4), LOG2E);
    __syncthreads();   // buf0 visible (also drains tile-1 loads; one-time)

    // QK^T for one 16-key subtile into a named register (static mt only)
    #define KQK(mt, CC)                                                        \
        do {                                                                   \
            short8 a0_ = *(const short8*)(KsB + ((mt) * 16 + l15) * 128 +      \
                                          ((quad * 16) ^ rsw));                \
            short8 a1_ = *(const short8*)(KsB + ((mt) * 16 + l15) * 128 +      \
                                          ((64 + quad * 16) ^ rsw));           \
            floatx4 t_ = (floatx4){0.f, 0.f, 0.f, 0.f};                        \
            t_ = __builtin_amdgcn_mfma_f32_16x16x32_bf16(a0_, Qf[0], t_,       \
                                                         0, 0, 0);             \
            t_ = __builtin_amdgcn_mfma_f32_16x16x32_bf16(a1_, Qf[1], t_,       \
                                                         0, 0, 0);             \
            (CC) = t_;                                                         \
        } while (0)

    // softmax + PV for one subtile (f2bf_hu: 2-op round-half-up; lst sums
    // the unrounded pv exactly as v11-v18 did — proven numerics)
    #define SMPV(mt, CC)                                                       \
        do {                                                                   \
            const float4 mv = mreg[mt];   /* already * LOG2E */                \
            const float pv0 = EXP2(fmaf((CC)[0], SCALE_LOG2E, mv.x));          \
            const float pv1 = EXP2(fmaf((CC)[1], SCALE_LOG2E, mv.y));          \
            const float pv2 = EXP2(fmaf((CC)[2], SCALE_LOG2E, mv.z));          \
            const float pv3 = EXP2(fmaf((CC)[3], SCALE_LOG2E, mv.w));          \
            lst += (pv0 + pv1) + (pv2 + pv3);                                  \
            short4v Af;                                                        \
            Af[0] = (short)f2bf_hu(pv0);                                       \
            Af[1] = (short)f2bf_hu(pv1);                                       \
            Af[2] = (short)f2bf_hu(pv2);                                       \
            Af[3] = (short)f2bf_hu(pv3);                                       \
            _Pragma("unroll")                                                  \
            for (int nt = 0; nt < 4; ++nt) {                                   \
                short4v Bf = *(const short4v*)(VsB + (nt * 16 + l15) * 128 +   \
                                               (((mt) * 32 + quad * 8) ^ rsw));\
                Of[nt] = mfma16x16x16(Af, Bf, Of[nt]);                         \
            }                                                                  \
        } while (0)

    for (int kt = 0; kt < SEQ / 64; ++kt) {
        const int buf = kt & 1;
        char* const KsB = (char*)Ks[buf];
        char* const VsB = (char*)Vs[buf];

        if (kt + 1 < SEQ / 64) {   // phase A: regs(tile kt+1) -> buf^1
            char* const KsW = (char*)Ks[buf ^ 1];
            char* const VsW = (char*)Vs[buf ^ 1];
            *(uint4*)(KsW + sw0) = kreg0;
            *(uint4*)(KsW + sw1) = kreg1;
            *(uint4*)(VsW + sw0) = vreg0;
            *(uint4*)(VsW + sw1) = vreg1;
        }
        if (kt + 2 < SEQ / 64)     // phase B: issue loads for tile kt+2
            LOADT(kt + 2);
        if (kt + 1 < SEQ / 64) {   // mask prefetch for tile kt+1
            #pragma unroll
            for (int mt = 0; mt < 4; ++mt)
                mnext[mt] = *(const float4*)(mrow + (kt + 1) * 64 + mt * 16 + quad * 4);
        }

        // ---- 2-deep mt-pipeline: QK(mt+1) in flight under softmax+PV(mt) --
        // T5: raise wave priority through the MFMA-dense region.
        __builtin_amdgcn_s_setprio(1);
        {
            floatx4 cA, cB;
            KQK(0, cA);
            KQK(1, cB);
            SMPV(0, cA);
            KQK(2, cA);
            SMPV(1, cB);
            KQK(3, cB);
            SMPV(2, cA);
            SMPV(3, cB);
        }
        __builtin_amdgcn_s_setprio(0);

        if (kt + 1 < SEQ / 64) {   // fold LOG2E (off critical path)
            #pragma unroll
            for (int mt = 0; mt < 4; ++mt) mreg[mt] = mul4(mnext[mt], LOG2E);
        }
        __syncthreads();   // ONE barrier: phase-A writes visible; buf free
    }
    #undef LOADT
    #undef KQK
    #undef SMPV

    // ---- epilogue: reduce l across quads, normalize, store ----
    lst += __shfl_xor(lst, 16);
    lst += __shfl_xor(lst, 32);   // lane with l15=q now holds full row sum
    #pragma unroll
    for (int r = 0; r < 4; ++r) {
        const float lrow = __shfl(lst, quad * 4 + r);   // row q = quad*4+r
        const float inv  = 1.0f / lrow;
        const int s = qb * 64 + wave * 16 + quad * 4 + r;
        float* orow = out + ((size_t)s * BATCH + bb) * HID + hh * 64;
        #pragma unroll
        for (int nt = 0; nt < 4; ++nt)
            orow[nt * 16 + l15] = Of[nt][r] * inv;
    }
}

// ---------------------------------------------------------------------------
extern "C" void kernel_launch(void* const* d_in, const int* in_sizes, int n_in,
                              void* d_out, int out_size, void* d_ws, size_t ws_size,
                              hipStream_t stream) {
    const float* x    = (const float*)d_in[0];
    const float* mask = (const float*)d_in[1];
    const float* Wq   = (const float*)d_in[2];
    const float* bq   = (const float*)d_in[3];
    const float* Wk   = (const float*)d_in[4];
    const float* bk   = (const float*)d_in[5];
    const float* Wv   = (const float*)d_in[6];
    const float* bv   = (const float*)d_in[7];
    float* out = (float*)d_out;

    const size_t per = (size_t)BH * SEQ * HDIM;   // 4,194,304 elems (8 MB bf16)
    unsigned short* qw = (unsigned short*)d_ws;   // 8 MB
    unsigned short* kw = qw + per;                // 8 MB
    unsigned short* vw = kw + per;                // 8 MB (V transposed [bh][d][s])
    unsigned short* xb = vw + per;                // 8 MB (x bf16)
    unsigned short* wt = xb + per;                // 6 MB (3x W^T bf16)

    convert_x<<<dim3(SEQ * BATCH * HID / 4 / 256), dim3(256), 0, stream>>>(x, xb);
    transpose_w<<<dim3(32, 32, 3), dim3(256), 0, stream>>>(Wq, Wk, Wv, wt);

    qkv_mfma<<<dim3(HID / 128, SEQ * BATCH / 128, 3), dim3(256), 0, stream>>>(
        xb, wt, bq, bk, bv, qw);

    attn_v20<<<dim3(SEQ / 64, BH), dim3(256), 0, stream>>>(qw, kw, vw, mask, out);
}